// Round 2
// baseline (312.869 us; speedup 1.0000x reference)
//
#include <hip/hip_runtime.h>
#include <math.h>

// ISTFT with ones-window, N_FFT=1024, HOP=256, center trim 512, LENGTH=600.
// Only frames t=0..4 contribute to output samples l in [512,1112).
//
// Kernel 1: per (b,segment) block, inverse real DFT at the needed n-range
//           only. Spectrum slice X[b,:,t] staged in LDS (broadcast reads in
//           the inner loop), angle-addition recurrence with sincosf refresh
//           every 128 steps. Raw (un-scaled) sums stored to ws.
// Kernel 2: overlap-add over valid frames + divide by (1024 * env), where
//           env = cover count (window is all-ones).

#define NFREQ 513
#define NFFT  1024
#define HOP   256
#define LEN   600
#define START 512
#define NB    64
#define NT    5    // frames that matter
#define NSEG  11   // 256-sample segments covering the needed (t,n) ranges

// Static segment table: (t, n_start, n_end) — covers exactly the (t,n) pairs
// that kernel 2 reads.
__constant__ int seg_t[NSEG]  = {0, 0,   1,   1,   1,   2, 2,   2,   3, 3,   4};
__constant__ int seg_n0[NSEG] = {512, 768, 256, 512, 768, 0, 256, 512, 0, 256, 0};
__constant__ int seg_n1[NSEG] = {768, 1024, 512, 768, 856, 256, 512, 600, 256, 344, 88};

__global__ __launch_bounds__(256) void idft_frames(const float* __restrict__ x,
                                                   float* __restrict__ S) {
    const int b   = blockIdx.x / NSEG;
    const int seg = blockIdx.x % NSEG;
    const int t   = seg_t[seg];

    __shared__ float2 X[NFREQ];

    // Stage spectrum slice: x[b,0,f,t,0:2] at float-offset ((b*513+f)*1024+t)*2.
    for (int f = threadIdx.x; f < NFREQ; f += blockDim.x) {
        const float* p = x + ((long)(b * NFREQ + f) * NFFT + t) * 2;
        X[f] = make_float2(p[0], p[1]);
    }
    __syncthreads();

    const int n = seg_n0[seg] + (int)threadIdx.x;
    if (n >= seg_n1[seg]) return;

    const float w = 6.28318530717958647692f / (float)NFFT; // 2*pi/1024

    // Step rotation by phi = 2*pi*n/1024.
    float cn, sn;
    sincosf((float)n * w, &sn, &cn);

    float acc = 0.0f;

    int k = 1;
    #pragma unroll
    for (int blk = 0; blk < 4; ++blk) {
        const int kend = min(512, k + 128);
        // Refresh (c,s) = (cos,sin)(2*pi*k*n/1024) exactly (mod 2*pi).
        const int m = (k * n) & (NFFT - 1);
        float c, s;
        sincosf((float)m * w, &s, &c);
        #pragma unroll 4
        for (; k < kend; ++k) {
            const float2 xv = X[k];           // uniform address -> broadcast
            acc = fmaf(xv.x, c, acc);
            acc = fmaf(-xv.y, s, acc);
            const float c2 = fmaf(c, cn, -(s * sn));
            s              = fmaf(s, cn,   c * sn);
            c = c2;
        }
    }

    // k=0 and k=512 (Nyquist): real parts only, weight 1 (c2r ignores their
    // imaginary parts, matching numpy/jax irfft semantics).
    const float nyq = (n & 1) ? -X[512].x : X[512].x;
    const float res = X[0].x + nyq + 2.0f * acc;

    S[((long)(b * NT + t)) * NFFT + n] = res;   // raw sum; scaled in kernel 2
}

__global__ __launch_bounds__(256) void ola_norm(const float* __restrict__ S,
                                                float* __restrict__ out) {
    const int i = blockIdx.x * blockDim.x + threadIdx.x;
    if (i >= NB * LEN) return;
    const int b  = i / LEN;
    const int lp = i - b * LEN;
    const int l  = lp + START;                        // [512, 1112)
    const int tlo = max(0, (l - (NFFT - HOP)) >> 8);  // first covering frame
    const int thi = l >> 8;                           // last covering frame (<=4)
    float sum = 0.0f;
    #pragma unroll
    for (int t = 0; t < NT; ++t) {
        if (t >= tlo && t <= thi) {
            sum += S[((long)(b * NT + t)) * NFFT + (l - HOP * t)];
        }
    }
    const float env = (float)(thi - tlo + 1);
    out[i] = sum / (1024.0f * env);
}

extern "C" void kernel_launch(void* const* d_in, const int* in_sizes, int n_in,
                              void* d_out, int out_size, void* d_ws, size_t ws_size,
                              hipStream_t stream) {
    const float* x = (const float*)d_in[0];
    float* out = (float*)d_out;
    float* S = (float*)d_ws;   // 64*5*1024 floats = 1.31 MB << ws_size

    idft_frames<<<dim3(NB * NSEG), dim3(256), 0, stream>>>(x, S);

    const int nout = NB * LEN;
    ola_norm<<<dim3((nout + 255) / 256), dim3(256), 0, stream>>>(S, out);
}

// Round 5
// 311.808 us; speedup vs baseline: 1.0034x; 1.0034x over previous
//
#include <hip/hip_runtime.h>
#include <math.h>

// ISTFT with ones-window, N_FFT=1024, HOP=256, center trim 512, LENGTH=600.
// Only frames t=0..4 contribute to output samples l in [512,1112).
//
// Kernel 1: per (b, segment, k-split) block, inverse real DFT partial sums at
//           the needed n only. Spectrum slice staged in LDS (uniform-address
//           broadcast reads). Inner loop uses the k <-> 512-k symmetry (two
//           accumulators share one (cos,sin)) and a Chebyshev 3-term
//           recurrence c_{k+1} = 2cos(nw) c_k - c_{k-1}, refreshed by sincosf
//           every 64 steps. 2-way k-split doubles occupancy and halves the
//           per-block serial chain; unroll 8 keeps ~16 ds_reads in flight.
// Kernel 2: sum k-split partials, overlap-add over valid frames, divide by
//           (1024 * cover-count)  [window is all-ones -> env = cover count].

#define NFREQ 513
#define NFFT  1024
#define HOP   256
#define LEN   600
#define START 512
#define NB    64
#define NT    5    // frames that matter
#define NSEG  11   // 256-sample segments covering the needed (t,n) ranges
#define NSPLIT 2   // k-range split for occupancy / chain length

// Static segment table: (t, n_start, n_end) — covers exactly the (t,n) pairs
// that kernel 2 reads.
__constant__ int seg_t[NSEG]  = {0, 0,   1,   1,   1,   2, 2,   2,   3, 3,   4};
__constant__ int seg_n0[NSEG] = {512, 768, 256, 512, 768, 0, 256, 512, 0, 256, 0};
__constant__ int seg_n1[NSEG] = {768, 1024, 512, 768, 856, 256, 512, 600, 256, 344, 88};

__global__ __launch_bounds__(256) void idft_frames(const float* __restrict__ x,
                                                   float* __restrict__ S) {
    const int b   = blockIdx.x / (NSEG * NSPLIT);
    const int r   = blockIdx.x % (NSEG * NSPLIT);
    const int seg = r / NSPLIT;
    const int sp  = r % NSPLIT;
    const int t   = seg_t[seg];

    __shared__ float2 X[NFREQ];

    // Stage spectrum slice: x[b,0,f,t,0:2] at float-offset ((b*513+f)*1024+t)*2.
    for (int f = threadIdx.x; f < NFREQ; f += blockDim.x) {
        const float* p = x + ((long)(b * NFREQ + f) * NFFT + t) * 2;
        X[f] = make_float2(p[0], p[1]);
    }
    __syncthreads();

    const int n = seg_n0[seg] + (int)threadIdx.x;
    if (n >= seg_n1[seg]) return;

    const float w = 6.28318530717958647692f / (float)NFFT; // 2*pi/1024

    // 2*cos(n*w) for the Chebyshev recurrence.
    float cn, sn;
    sincosf((float)n * w, &sn, &cn);
    const float t2 = 2.0f * cn;

    float acc1 = 0.0f;  // sum over k in this split's range
    float acc2 = 0.0f;  // mirrored k' = 512-k (sign applied at the end)

    // Split 0: pairs k = 1..128.  Split 1: pairs k = 129..255.
    int k            = (sp == 0) ? 1   : 129;
    const int ksplit = (sp == 0) ? 129 : 256;

    #pragma unroll
    for (int blk = 0; blk < 2; ++blk) {
        // Refresh (c,s) = (cos,sin)(k*n*w) and the k-1 pair, exact mod 2*pi.
        const int m1 = (k * n) & (NFFT - 1);
        const int m0 = ((k - 1) * n) & (NFFT - 1);
        float c, s, cm1, sm1;
        sincosf((float)m1 * w, &s, &c);
        sincosf((float)m0 * w, &sm1, &cm1);
        const int kstop = min(ksplit, k + 64);
        #pragma unroll 8
        for (; k < kstop; ++k) {
            const float2 xa = X[k];        // uniform address -> broadcast
            const float2 xb = X[512 - k];  // uniform address -> broadcast
            acc1 = fmaf(xa.x, c, acc1);
            acc1 = fmaf(-xa.y, s, acc1);
            acc2 = fmaf(xb.x, c, acc2);
            acc2 = fmaf(xb.y, s, acc2);
            const float cnx = fmaf(t2, c, -cm1);
            const float snx = fmaf(t2, s, -sm1);
            cm1 = c; sm1 = s; c = cnx; s = snx;
        }
    }

    // sigma = (-1)^n applies to the mirrored (512-k) accumulator.
    const float sigma = (n & 1) ? -1.0f : 1.0f;
    float res = 2.0f * (acc1 + sigma * acc2);

    if (sp == 0) {
        // k = 256: cos(n*pi/2), sin(n*pi/2) in {1,0,-1} by n mod 4.
        float c256, s256;
        switch (n & 3) {
            case 0:  c256 = 1.0f;  s256 = 0.0f;  break;
            case 1:  c256 = 0.0f;  s256 = 1.0f;  break;
            case 2:  c256 = -1.0f; s256 = 0.0f;  break;
            default: c256 = 0.0f;  s256 = -1.0f; break;
        }
        const float term256 = X[256].x * c256 - X[256].y * s256;
        // k=0 and k=512 (Nyquist): real parts only, weight 1 (c2r ignores
        // their imaginary parts, matching numpy/jax irfft semantics).
        const float nyq = (n & 1) ? -X[512].x : X[512].x;
        res += X[0].x + nyq + 2.0f * term256;
    }

    S[(((long)(b * NT + t)) * NSPLIT + sp) * NFFT + n] = res;  // raw partial
}

__global__ __launch_bounds__(256) void ola_norm(const float* __restrict__ S,
                                                float* __restrict__ out) {
    const int i = blockIdx.x * blockDim.x + threadIdx.x;
    if (i >= NB * LEN) return;
    const int b  = i / LEN;
    const int lp = i - b * LEN;
    const int l  = lp + START;                        // [512, 1112)
    const int tlo = max(0, (l - (NFFT - HOP)) >> 8);  // first covering frame
    const int thi = l >> 8;                           // last covering frame (<=4)
    float sum = 0.0f;
    #pragma unroll
    for (int t = 0; t < NT; ++t) {
        if (t >= tlo && t <= thi) {
            const long base = (((long)(b * NT + t)) * NSPLIT) * NFFT + (l - HOP * t);
            sum += S[base] + S[base + NFFT];
        }
    }
    const float env = (float)(thi - tlo + 1);
    out[i] = sum / (1024.0f * env);
}

extern "C" void kernel_launch(void* const* d_in, const int* in_sizes, int n_in,
                              void* d_out, int out_size, void* d_ws, size_t ws_size,
                              hipStream_t stream) {
    const float* x = (const float*)d_in[0];
    float* out = (float*)d_out;
    float* S = (float*)d_ws;   // 64*5*2*1024 floats = 2.62 MB << ws_size

    idft_frames<<<dim3(NB * NSEG * NSPLIT), dim3(256), 0, stream>>>(x, S);

    const int nout = NB * LEN;
    ola_norm<<<dim3((nout + 255) / 256), dim3(256), 0, stream>>>(S, out);
}